// Round 5
// baseline (354.854 us; speedup 1.0000x reference)
//
#include <hip/hip_runtime.h>
#include <hip/hip_bf16.h>
#include <cstddef>
#include <cstdint>

// Problem constants
#define B_  4
#define T_  4096
#define D_  1024
#define H_  16
#define DH_ 64
#define R_  256
#define BT_ (B_ * T_)       // 16384
#define TWO_D_ (2 * D_)     // 2048

typedef __attribute__((ext_vector_type(8))) short short8;
typedef __attribute__((ext_vector_type(4))) float f32x4;
typedef __attribute__((ext_vector_type(16))) float f32x16;

__device__ __forceinline__ float elu1(float x) {
    return x > 0.0f ? x + 1.0f : __expf(x);
}

__device__ __forceinline__ float bf2f(short u) {
    union { uint32_t i; float f; } c;
    c.i = ((uint32_t)(uint16_t)u) << 16;
    return c.f;
}

typedef __attribute__((address_space(1))) void void_g;
typedef __attribute__((address_space(3))) void void_l;
__device__ __forceinline__ void gld_lds16(const void* g, void* l) {
    __builtin_amdgcn_global_load_lds(
        (const void_g*)(uintptr_t)g,
        (void_l*)(uint32_t)(uintptr_t)l,
        16, 0, 0);
}

// ---------------------------------------------------------------------------
// bf16 MFMA GEMM: C[M,N] = A[M,K] @ Bt[N,K]^T + bias.
// 128x128x32 tiles, 4 waves (2x2), each wave 2x2 of 32x32x16 MFMA.
// LDS: [row][32 k] with 16B-chunk XOR swizzle phys_c = c ^ ((row>>1)&3)
// applied at staging (global-side) and fragment reads -> conflict-free b128.
// 1-D grid, 8-row-strip col-major swizzle for XCD L2 locality.
// EPI 0: none; 1: elu1 all; 2: elu1 on k-part; 3: split q/xd store.
// BROW: bias indexed by row (transposed-output GEMM3'), EPI2 tests row.
// ---------------------------------------------------------------------------
#define BM 128
#define BN 128
#define BK 32

__device__ __forceinline__ void store_out(float* p, float v) { *p = v; }
__device__ __forceinline__ void store_out(__hip_bfloat16* p, float v) { *p = __float2bfloat16(v); }

template<int EPI, bool BROW, typename OT>
__global__ __launch_bounds__(256) void gemm_bf16(
    const __hip_bfloat16* __restrict__ A,
    const __hip_bfloat16* __restrict__ Bt,
    const float* __restrict__ bias,
    OT* __restrict__ C,
    OT* __restrict__ C2,
    int M, int N, int K)
{
    __shared__ alignas(16) __hip_bfloat16 As[BM * BK];
    __shared__ alignas(16) __hip_bfloat16 Bs[BN * BK];

    // swizzle: strips of 8 row-tiles, col-major within strip (M/BM % 8 == 0)
    const int nbx = N / BN;
    const int id = blockIdx.x;
    const int strip = id / (8 * nbx);
    const int wi = id % (8 * nbx);
    const int bm = (strip * 8 + (wi & 7)) * BM;
    const int bn = (wi >> 3) * BN;

    const int tid  = threadIdx.x;
    const int lane = tid & 63;
    const int wm   = (tid >> 7) * 64;         // wave row offset (0/64)
    const int wn   = ((tid >> 6) & 1) * 64;   // wave col offset (0/64)
    const int l31  = lane & 31;
    const int hi   = lane >> 5;               // 0/1

    f32x16 acc[2][2] = {};

    // staging: LDS chunk n (16 B at n*16) holds global (row=n>>2,
    // k-octet u=(n&3)^((n>>3)&3)) — the XOR permutes global source only;
    // LDS side stays contiguous (global_load_lds lane*16 semantics).
    const int c0 = tid, c1 = tid + 256;
    const int u0 = (c0 & 3) ^ ((c0 >> 3) & 3);
    const int u1 = (c1 & 3) ^ ((c1 >> 3) & 3);
    const __hip_bfloat16* a0 = A  + (size_t)(bm + (c0 >> 2)) * K + u0 * 8;
    const __hip_bfloat16* a1 = A  + (size_t)(bm + (c1 >> 2)) * K + u1 * 8;
    const __hip_bfloat16* b0 = Bt + (size_t)(bn + (c0 >> 2)) * K + u0 * 8;
    const __hip_bfloat16* b1 = Bt + (size_t)(bn + (c1 >> 2)) * K + u1 * 8;

    for (int k0 = 0; k0 < K; k0 += BK) {
        gld_lds16(a0 + k0, As + c0 * 8);
        gld_lds16(a1 + k0, As + c1 * 8);
        gld_lds16(b0 + k0, Bs + c0 * 8);
        gld_lds16(b1 + k0, Bs + c1 * 8);
        __syncthreads();

        // fragments: A row m=lane&31 (+tile), k=(lane>>5)*8+j, kstep s adds 16
        short8 af[2][2], bf[2][2];
#pragma unroll
        for (int i = 0; i < 2; ++i)
#pragma unroll
            for (int s = 0; s < 2; ++s) {
                const int ca = s * 2 + hi;
                const int ra = wm + i * 32 + l31;
                af[i][s] = *(const short8*)(As + ra * 32 + (ca ^ ((ra >> 1) & 3)) * 8);
                const int rb = wn + i * 32 + l31;
                bf[i][s] = *(const short8*)(Bs + rb * 32 + (ca ^ ((rb >> 1) & 3)) * 8);
            }
#pragma unroll
        for (int s = 0; s < 2; ++s)
#pragma unroll
            for (int i = 0; i < 2; ++i)
#pragma unroll
                for (int j = 0; j < 2; ++j)
                    acc[i][j] = __builtin_amdgcn_mfma_f32_32x32x16_bf16(
                        af[i][s], bf[j][s], acc[i][j], 0, 0, 0);
        __syncthreads();
    }

    // C/D layout (32x32): col=lane&31, row=(reg&3)+8*(reg>>2)+4*(lane>>5)
    const int rbase = bm + wm + 4 * hi;

    if (EPI == 3) {
        // cols < 1024: q = elu1(.) at stride 1024; cols >= 1024: xd stride 256
        const bool qreg = (bn < 1024);
#pragma unroll
        for (int j = 0; j < 2; ++j) {
            const int col = bn + wn + j * 32 + l31;
            const float bv = bias[col];
#pragma unroll
            for (int i = 0; i < 2; ++i)
#pragma unroll
                for (int r = 0; r < 16; ++r) {
                    const int row = rbase + i * 32 + (r & 3) + 8 * (r >> 2);
                    float v = acc[i][j][r] + bv;
                    if (qreg) store_out(C + (size_t)row * 1024 + col, elu1(v));
                    else      store_out(C2 + (size_t)row * 256 + (col - 1024), v);
                }
        }
        return;
    }

    float brow[2][16];
    if (BROW) {
#pragma unroll
        for (int i = 0; i < 2; ++i)
#pragma unroll
            for (int r = 0; r < 16; ++r)
                brow[i][r] = bias[rbase + i * 32 + (r & 3) + 8 * (r >> 2)];
    }
#pragma unroll
    for (int j = 0; j < 2; ++j) {
        const int col = bn + wn + j * 32 + l31;
        const float bv = BROW ? 0.0f : bias[col];
        const bool kp_col = ((col & 127) < 64);
#pragma unroll
        for (int i = 0; i < 2; ++i) {
#pragma unroll
            for (int r = 0; r < 16; ++r) {
                const int row = rbase + i * 32 + (r & 3) + 8 * (r >> 2);
                float v = acc[i][j][r] + (BROW ? brow[i][r] : bv);
                if (EPI == 1) v = elu1(v);
                else if (EPI == 2) {
                    const bool kp = BROW ? ((row & 127) < 64) : kp_col;
                    if (kp) v = elu1(v);
                }
                store_out(C + (size_t)row * N + col, v);
            }
        }
    }
}

// ---------------------------------------------------------------------------
__global__ __launch_bounds__(256) void cast_bf16_kernel(
    const float* __restrict__ s, __hip_bfloat16* __restrict__ d, int n)
{
    const int i = (blockIdx.x * 256 + threadIdx.x) * 8;
    if (i >= n) return;
    float4 v0 = *(const float4*)(s + i);
    float4 v1 = *(const float4*)(s + i + 4);
    __hip_bfloat16 t[8];
    t[0] = __float2bfloat16(v0.x); t[1] = __float2bfloat16(v0.y);
    t[2] = __float2bfloat16(v0.z); t[3] = __float2bfloat16(v0.w);
    t[4] = __float2bfloat16(v1.x); t[5] = __float2bfloat16(v1.y);
    t[6] = __float2bfloat16(v1.z); t[7] = __float2bfloat16(v1.w);
    *(short8*)(d + i) = *(const short8*)t;
}

__global__ __launch_bounds__(256) void transpose_cast(
    const float* __restrict__ W, __hip_bfloat16* __restrict__ Wt, int K, int N)
{
    __shared__ float t[32][33];
    const int n0 = blockIdx.x * 32, k0 = blockIdx.y * 32;
    const int c = threadIdx.x & 31, r = threadIdx.x >> 5;
#pragma unroll
    for (int rr = r; rr < 32; rr += 8)
        t[rr][c] = W[(size_t)(k0 + rr) * N + n0 + c];
    __syncthreads();
#pragma unroll
    for (int rr = r; rr < 32; rr += 8)
        Wt[(size_t)(n0 + rr) * K + k0 + c] = __float2bfloat16(t[c][rr]);
}

__global__ __launch_bounds__(256) void concat_bias(
    const float* __restrict__ bq, const float* __restrict__ bd,
    float* __restrict__ o)
{
    const int i = blockIdx.x * 256 + threadIdx.x;   // 0..1279
    o[i] = (i < 1024) ? bq[i] : bd[i - 1024];
}

// ---------------------------------------------------------------------------
// ctx_mfma: ctx[bh][d][e] = sum_t K^T[d][t] * V^T[e][t]; ksum via ones-trick.
// kvT layout: [2048][BT_] bf16; rows h*128+0..63 = K^T, 64..127 = V^T.
// ---------------------------------------------------------------------------
#define CHT 512

__global__ __launch_bounds__(256) void ctx_mfma(
    const __hip_bfloat16* __restrict__ kvT, float* __restrict__ ctx,
    float* __restrict__ ksum)
{
    __shared__ alignas(16) unsigned char smem[40960];
    float* red0 = (float*)smem;
    float* red1 = (float*)(smem + 20480);

    const int bh = blockIdx.x >> 3;
    const int chunk = blockIdx.x & 7;
    const int b = bh >> 4;
    const int h = bh & 15;
    const int tid = threadIdx.x;
    const int lane = tid & 63;
    const int w = tid >> 6;
    const int r15 = lane & 15;
    const int kg  = lane >> 4;

    f32x4 acc[4][4] = {};
    f32x4 acc4[4] = {};

    const short one = (short)0x3F80;
    const short8 bfv = (r15 == 0)
        ? (short8){one, one, one, one, one, one, one, one}
        : (short8){0, 0, 0, 0, 0, 0, 0, 0};

    const size_t tbase = (size_t)b * T_ + (size_t)chunk * CHT;
    const __hip_bfloat16* src = kvT + (size_t)(h * 128) * BT_ + tbase;

    for (int it = 0; it < CHT / 128; ++it) {
#pragma unroll
        for (int r = 0; r < 8; ++r) {
            const int c = r * 256 + tid;
            const int s = c >> 9, j = (c >> 2) & 127, u = c & 3;
            gld_lds16(src + (size_t)j * BT_ + it * 128 + s * 32 + u * 8,
                      smem + c * 16);
        }
        __syncthreads();

        const __hip_bfloat16* Ls = (const __hip_bfloat16*)smem;
        short8 af[4], bf[4];
#pragma unroll
        for (int i = 0; i < 4; ++i) {
            af[i] = *(const short8*)(Ls + (w * 128 + i * 16 + r15) * 32 + kg * 8);
            bf[i] = *(const short8*)(Ls + (w * 128 + 64 + i * 16 + r15) * 32 + kg * 8);
        }
#pragma unroll
        for (int i = 0; i < 4; ++i) {
#pragma unroll
            for (int j = 0; j < 4; ++j)
                acc[i][j] = __builtin_amdgcn_mfma_f32_16x16x32_bf16(af[i], bf[j], acc[i][j], 0, 0, 0);
            acc4[i] = __builtin_amdgcn_mfma_f32_16x16x32_bf16(af[i], bfv, acc4[i], 0, 0, 0);
        }
        __syncthreads();
    }

    const int q4 = lane >> 4;
    auto wr = [&](float* reg) {
#pragma unroll
        for (int i = 0; i < 4; ++i) {
#pragma unroll
            for (int r = 0; r < 4; ++r) {
                const int row = i * 16 + q4 * 4 + r;
#pragma unroll
                for (int j = 0; j < 4; ++j) reg[row * 80 + j * 16 + r15] = acc[i][j][r];
                reg[row * 80 + 64 + r15] = acc4[i][r];
            }
        }
    };
    auto rd = [&](const float* reg) {
#pragma unroll
        for (int i = 0; i < 4; ++i) {
#pragma unroll
            for (int r = 0; r < 4; ++r) {
                const int row = i * 16 + q4 * 4 + r;
#pragma unroll
                for (int j = 0; j < 4; ++j) acc[i][j][r] += reg[row * 80 + j * 16 + r15];
                acc4[i][r] += reg[row * 80 + 64 + r15];
            }
        }
    };

    if (w == 1) wr(red0);
    if (w == 3) wr(red1);
    __syncthreads();
    if (w == 0) rd(red0);
    if (w == 2) rd(red1);
    __syncthreads();
    if (w == 2) wr(red0);
    __syncthreads();
    if (w == 0) { rd(red0); wr(red0); }
    __syncthreads();

    float* cdst = ctx + (size_t)bh * 4096;
#pragma unroll
    for (int r = 0; r < 16; ++r) {
        const int idx = r * 256 + tid;
        const int d = idx >> 6, e = idx & 63;
        atomicAdd(cdst + idx, red0[d * 80 + e]);
    }
    if (tid < 64) atomicAdd(ksum + bh * 64 + tid, red0[tid * 80 + 64]);
}

// ---------------------------------------------------------------------------
__global__ __launch_bounds__(256) void pack_ctx(
    const float* __restrict__ ctx, __hip_bfloat16* __restrict__ ctxT)
{
    __shared__ float L[64 * 65];
    const int bh = blockIdx.x;
    const int tid = threadIdx.x;
#pragma unroll
    for (int r = 0; r < 16; ++r) {
        const int idx = r * 256 + tid;
        L[(idx >> 6) * 65 + (idx & 63)] = ctx[(size_t)bh * 4096 + idx];
    }
    __syncthreads();
#pragma unroll
    for (int r = 0; r < 16; ++r) {
        const int idx = r * 256 + tid;
        ctxT[(size_t)bh * 4096 + idx] =
            __float2bfloat16(L[(idx & 63) * 65 + (idx >> 6)]);
    }
}

// ---------------------------------------------------------------------------
// out_mfma: out[t][h*64+e] = z_t * sum_d q[t][d] * ctx[d][e]
// ---------------------------------------------------------------------------
__global__ __launch_bounds__(256) void out_mfma(
    const __hip_bfloat16* __restrict__ qb, const __hip_bfloat16* __restrict__ ctxT,
    const float* __restrict__ ksum, __hip_bfloat16* __restrict__ outb)
{
    __shared__ alignas(16) unsigned char As[256 * 128];
    __shared__ alignas(16) unsigned char Bs[64 * 128];
    __shared__ float ksumL[64];
    __shared__ float zbuf[256];

    const int bh = blockIdx.x >> 4;
    const int tile = blockIdx.x & 15;
    const int b = bh >> 4;
    const int h = bh & 15;
    const int tid = threadIdx.x;
    const int lane = tid & 63;
    const int w = tid >> 6;
    const int r15 = lane & 15;
    const int kg  = lane >> 4;

    const size_t trow0 = (size_t)b * T_ + (size_t)tile * 256;

#pragma unroll
    for (int r = 0; r < 8; ++r) {
        const int c = r * 256 + tid;
        const int row = c >> 3, slot = c & 7, u = slot ^ (row & 7);
        gld_lds16(qb + (trow0 + row) * D_ + h * 64 + u * 8, As + c * 16);
    }
#pragma unroll
    for (int r = 0; r < 2; ++r) {
        const int c = r * 256 + tid;
        const int row = c >> 3, slot = c & 7, u = slot ^ (row & 7);
        gld_lds16(ctxT + (size_t)bh * 4096 + row * 64 + u * 8, Bs + c * 16);
    }
    if (tid < 64) ksumL[tid] = ksum[bh * 64 + tid];
    __syncthreads();

    short8 af[4][2], bf[4][2];
#pragma unroll
    for (int i = 0; i < 4; ++i)
#pragma unroll
        for (int s = 0; s < 2; ++s) {
            const int m = w * 64 + i * 16 + r15;
            const int n = i * 16 + r15;
            const int uk = s * 4 + kg;
            af[i][s] = *(const short8*)(As + m * 128 + ((uk ^ (m & 7)) * 16));
            bf[i][s] = *(const short8*)(Bs + n * 128 + ((uk ^ (n & 7)) * 16));
        }

    f32x4 acc[4][4] = {};
#pragma unroll
    for (int s = 0; s < 2; ++s)
#pragma unroll
        for (int i = 0; i < 4; ++i)
#pragma unroll
            for (int j = 0; j < 4; ++j)
                acc[i][j] = __builtin_amdgcn_mfma_f32_16x16x32_bf16(af[i][s], bf[j][s], acc[i][j], 0, 0, 0);

    float dsum[4];
#pragma unroll
    for (int i = 0; i < 4; ++i) {
        float s0 = 0.0f;
#pragma unroll
        for (int s = 0; s < 2; ++s)
#pragma unroll
            for (int j8 = 0; j8 < 8; ++j8)
                s0 += bf2f(af[i][s][j8]) * ksumL[s * 32 + kg * 8 + j8];
        s0 += __shfl_xor(s0, 16);
        s0 += __shfl_xor(s0, 32);
        dsum[i] = s0;
    }
    if (lane < 16) {
#pragma unroll
        for (int i = 0; i < 4; ++i)
            zbuf[w * 64 + i * 16 + lane] = 1.0f / (dsum[i] + 1e-6f);
    }
    __syncthreads();

    const int q4 = lane >> 4;
#pragma unroll
    for (int i = 0; i < 4; ++i) {
#pragma unroll
        for (int r = 0; r < 4; ++r) {
            const int m = w * 64 + i * 16 + q4 * 4 + r;
            const float z = zbuf[m];
#pragma unroll
            for (int j = 0; j < 4; ++j) {
                outb[(trow0 + m) * D_ + h * 64 + j * 16 + r15] =
                    __float2bfloat16(acc[i][j][r] * z);
            }
        }
    }
}

// ---------------------------------------------------------------------------
extern "C" void kernel_launch(void* const* d_in, const int* in_sizes, int n_in,
                              void* d_out, int out_size, void* d_ws, size_t ws_size,
                              hipStream_t stream) {
    const float* x  = (const float*)d_in[0];
    const float* Wq = (const float*)d_in[1];
    const float* bq = (const float*)d_in[2];
    const float* Wd = (const float*)d_in[3];
    const float* bd = (const float*)d_in[4];
    const float* Wu = (const float*)d_in[5];
    const float* bu = (const float*)d_in[6];
    const float* Wo = (const float*)d_in[7];
    const float* bo = (const float*)d_in[8];
    float* out = (float*)d_out;

    __hip_bfloat16* xb    = (__hip_bfloat16*)d_ws;            // BT*D
    __hip_bfloat16* WqdT  = xb    + (size_t)BT_ * D_;         // [1280][1024]
    __hip_bfloat16* WuT   = WqdT  + (size_t)1280 * D_;        // [2048][256]
    __hip_bfloat16* WoT   = WuT   + (size_t)TWO_D_ * R_;      // [1024][1024]
    __hip_bfloat16* xdb   = WoT   + (size_t)D_ * D_;          // BT*R
    __hip_bfloat16* kvT   = xdb   + (size_t)BT_ * R_;         // 2048*BT
    __hip_bfloat16* qb    = kvT   + (size_t)TWO_D_ * BT_;     // BT*D
    float* bias_qd = (float*)(qb + (size_t)BT_ * D_);         // 1280
    float* ctx  = bias_qd + 1280;                             // 64*4096
    float* ksum = ctx + (size_t)B_ * H_ * DH_ * DH_;          // 64*64
    __hip_bfloat16* ctxT = (__hip_bfloat16*)(ksum + B_ * H_ * DH_);  // 64*4096
    __hip_bfloat16* outb = xb;   // alias: xb dead after fused GEMM12

    hipMemsetAsync(ctx, 0,
        (size_t)(B_ * H_ * DH_ * DH_ + B_ * H_ * DH_) * sizeof(float), stream);

    cast_bf16_kernel<<<(BT_ * D_) / (8 * 256), 256, 0, stream>>>(x, xb, BT_ * D_);
    transpose_cast<<<dim3(D_ / 32, D_ / 32), 256, 0, stream>>>(Wq, WqdT, D_, D_);
    transpose_cast<<<dim3(R_ / 32, D_ / 32), 256, 0, stream>>>(Wd, WqdT + (size_t)D_ * D_, D_, R_);
    transpose_cast<<<dim3(TWO_D_ / 32, R_ / 32), 256, 0, stream>>>(Wu, WuT, R_, TWO_D_);
    transpose_cast<<<dim3(D_ / 32, D_ / 32), 256, 0, stream>>>(Wo, WoT, D_, D_);
    concat_bias<<<5, 256, 0, stream>>>(bq, bd, bias_qd);

    // 1+2) fused: [q | xd] = x @ [Wq|Wd] + [bq|bd]; elu1 + split store
    gemm_bf16<3, false, __hip_bfloat16><<<(BT_ / BM) * (1280 / BN), 256, 0, stream>>>(
        xb, WqdT, bias_qd, qb, xdb, BT_, 1280, D_);
    // 3) kvT[j][t] = Wu^T @ xd^T + bu[j], elu1 on rows (j&127)<64
    gemm_bf16<2, true, __hip_bfloat16><<<(TWO_D_ / BM) * (BT_ / BN), 256, 0, stream>>>(
        WuT, xdb, bu, kvT, nullptr, TWO_D_, BT_, R_);
    // 4) ctx + ksum via MFMA
    ctx_mfma<<<64 * (T_ / CHT), 256, 0, stream>>>(kvT, ctx, ksum);
    // 5) pack ctx -> bf16 transposed
    pack_ctx<<<64, 256, 0, stream>>>(ctx, ctxT);
    // 6) out = z * (q @ ctx)
    out_mfma<<<64 * 16, 256, 0, stream>>>(qb, ctxT, ksum, outb);
    // 7) final = outb @ Wo + bo
    gemm_bf16<0, false, float><<<(BT_ / BM) * (D_ / BN), 256, 0, stream>>>(
        outb, WoT, bo, out, nullptr, BT_, D_, D_);
}